// Round 6
// baseline (276.917 us; speedup 1.0000x reference)
//
#include <hip/hip_runtime.h>
#include <hip/hip_bf16.h>

#define BATCHN 16
#define SEQ 4096
#define HIDDEN 128
#define STATE 256
#define MTOT (BATCHN*SEQ)    // 65536
#define NCHUNK 64
#define LCHUNK 64            // SEQ / NCHUNK
#define NTILE (MTOT/64)      // 1024 tiles

typedef __bf16 bf16;
typedef __bf16 bf16x4 __attribute__((ext_vector_type(4)));
typedef __bf16 bf16x8 __attribute__((ext_vector_type(8)));
typedef float f32x4 __attribute__((ext_vector_type(4)));

__device__ __forceinline__ void scan_params(const float* __restrict__ A_diag,
        const float* __restrict__ steps, int n,
        float& m11, float& m12, float& m21, float& m22, float& c1, float& c2) {
    float st = 1.0f / (1.0f + expf(-steps[n]));
    float A  = fmaxf(A_diag[n], 0.0f);
    float s2A = st * st * A;
    float schur = 1.0f / (1.0f + s2A);
    m11 = 1.0f - s2A * schur;
    m12 = -st * A * schur;
    m21 = st * schur;
    m22 = schur;
    c1 = m11 * st;
    c2 = m21 * st;
}

// load 8 consecutive fp32 -> bf16x8 fragment (L2-hot B/C panels)
__device__ __forceinline__ bf16x8 load_frag_f32(const float* __restrict__ src) {
    float4 a = *reinterpret_cast<const float4*>(src);
    float4 b = *reinterpret_cast<const float4*>(src + 4);
    bf16x8 r = { (bf16)a.x, (bf16)a.y, (bf16)a.z, (bf16)a.w,
                 (bf16)b.x, (bf16)b.y, (bf16)b.z, (bf16)b.w };
    return r;
}

// Single fused kernel. Tile id via atomic ticket (rocPRIM decoupled-scan style):
// ticket order == block start order, and tile vbid only waits on smaller vbids
// of the same batch -> deadlock-free at ANY occupancy (no cooperative launch).
__global__ __launch_bounds__(256, 4) void fused_k(
        const float* __restrict__ x, const float* __restrict__ A_diag,
        const float* __restrict__ steps, const float* __restrict__ Bm,
        const float* __restrict__ Cm, const float* __restrict__ Dv,
        float* __restrict__ cs, int* __restrict__ sync_buf,   // [0]=ticket, [16..16+1023]=flags
        float* __restrict__ out) {
    __shared__ bf16 bu[64][264];                 // 33792 B; aliased as xl / ldsF
    bf16 (*xl)[136]    = reinterpret_cast<bf16(*)[136]>(&bu[0][0]);
    float (*ldsF)[132] = reinterpret_cast<float(*)[132]>(&bu[0][0]);
    __shared__ int vbid_s;

    const int tid = threadIdx.x;
    if (tid == 0) vbid_s = atomicAdd(sync_buf, 1);
    __syncthreads();
    const int bid = vbid_s;                      // virtual tile id
    const int m0  = bid * 64;
    const int wid = tid >> 6, lane = tid & 63;
    const int lr = lane & 15, lk = (lane >> 4) * 8;
    const int n0 = wid * 64, h0 = wid * 32;
    const int batch = bid >> 6;
    const int chunk = bid & (NCHUNK - 1);
    const int n = tid;                           // state index in scan phases
    const int mrow = (lane >> 4) * 4;
    int* flags = sync_buf + 16;

    // ---------------- phase 1: stage x -> GEMM1 -> scanA -> publish cs ----------------
    #pragma unroll
    for (int p = 0; p < 8; ++p) {
        int flat = p * 256 + tid;                // 64 rows x 32 float4
        int row = flat >> 5, c4 = flat & 31;
        float4 v = *reinterpret_cast<const float4*>(&x[(size_t)(m0 + row) * HIDDEN + c4 * 4]);
        bf16x4 w = { (bf16)v.x, (bf16)v.y, (bf16)v.z, (bf16)v.w };
        *reinterpret_cast<bf16x4*>(&xl[row][c4 * 4]) = w;
    }
    __syncthreads();

    f32x4 acc[4][4];
    #pragma unroll
    for (int i = 0; i < 4; ++i)
        #pragma unroll
        for (int j = 0; j < 4; ++j) acc[i][j] = f32x4{0.f, 0.f, 0.f, 0.f};
    #pragma unroll
    for (int ks = 0; ks < 4; ++ks) {
        int k = ks * 32 + lk;
        bf16x8 a[4], bfr[4];
        #pragma unroll
        for (int mf = 0; mf < 4; ++mf)
            a[mf] = *reinterpret_cast<const bf16x8*>(&xl[mf * 16 + lr][k]);
        #pragma unroll
        for (int nf = 0; nf < 4; ++nf)
            bfr[nf] = load_frag_f32(&Bm[(size_t)(n0 + nf * 16 + lr) * HIDDEN + k]);
        #pragma unroll
        for (int mf = 0; mf < 4; ++mf)
            #pragma unroll
            for (int nf = 0; nf < 4; ++nf)
                acc[mf][nf] = __builtin_amdgcn_mfma_f32_16x16x32_bf16(a[mf], bfr[nf], acc[mf][nf], 0, 0, 0);
    }
    __syncthreads();                              // all xl reads done before bu overwrite
    #pragma unroll
    for (int mf = 0; mf < 4; ++mf)
        #pragma unroll
        for (int nf = 0; nf < 4; ++nf)
            #pragma unroll
            for (int r = 0; r < 4; ++r)
                bu[mf * 16 + mrow + r][n0 + nf * 16 + lr] = (bf16)acc[mf][nf][r];

    float m11, m12, m21, m22, c1, c2;
    scan_params(A_diag, steps, n, m11, m12, m21, m22, c1, c2);
    __syncthreads();
    {
        float s1 = 0.f, s2 = 0.f;
        #pragma unroll 8
        for (int t = 0; t < LCHUNK; ++t) {
            float v = (float)bu[t][n];
            float ns1 = fmaf(m11, s1, fmaf(m12, s2, c1 * v));
            float ns2 = fmaf(m21, s1, fmaf(m22, s2, c2 * v));
            s1 = ns1; s2 = ns2;
        }
        size_t base = ((size_t)bid * 2) * STATE + n;   // bid == batch*NCHUNK+chunk
        cs[base] = s1;                                  // inclusive local chunk state
        cs[base + STATE] = s2;
    }
    __threadfence();                              // release: drain cs writes device-scope
    __syncthreads();                              // all threads' writes before flag
    if (tid == 0)
        __hip_atomic_store(&flags[bid], 1, __ATOMIC_RELEASE, __HIP_MEMORY_SCOPE_AGENT);

    // ---------------- phase 2: gather exclusive prefix from predecessors ----------------
    float S1 = 0.f, S2 = 0.f;
    if (chunk > 0) {
        if (tid == 0) {
            #pragma nounroll
            for (int j = 0; j < chunk; ++j) {
                const int* f = &flags[batch * NCHUNK + j];
                while (__hip_atomic_load(f, __ATOMIC_RELAXED, __HIP_MEMORY_SCOPE_AGENT) == 0)
                    __builtin_amdgcn_s_sleep(2);
            }
        }
        __syncthreads();
        __threadfence();                          // acquire: invalidate stale L1/L2 lines
        float p11 = m11, p12 = m12, p21 = m21, p22 = m22;
        #pragma unroll
        for (int i = 0; i < 6; ++i) {             // M^64 via squaring
            float q11 = p11 * p11 + p12 * p21;
            float q12 = p11 * p12 + p12 * p22;
            float q21 = p21 * p11 + p22 * p21;
            float q22 = p21 * p12 + p22 * p22;
            p11 = q11; p12 = q12; p21 = q21; p22 = q22;
        }
        #pragma unroll 4
        for (int j = 0; j < chunk; ++j) {         // S = M64*S + v_j, ascending j
            size_t base = ((size_t)(batch * NCHUNK + j) * 2) * STATE + n;
            float q1 = cs[base], q2 = cs[base + STATE];
            float n1 = fmaf(p11, S1, fmaf(p12, S2, q1));
            float n2 = fmaf(p21, S1, fmaf(p22, S2, q2));
            S1 = n1; S2 = n2;
        }
    }

    // ---------------- phase 3: scanC on resident bu -> GEMM2 -> D*x ----------------
    // T14: issue epilogue x loads now; scanC+GEMM2 hide the latency
    float4 xep[8];
    #pragma unroll
    for (int p = 0; p < 8; ++p) {
        int flat = p * 256 + tid;
        int row = flat >> 5, c4 = flat & 31;
        xep[p] = *reinterpret_cast<const float4*>(&x[(size_t)(m0 + row) * HIDDEN + c4 * 4]);
    }
    {
        float s1 = S1, s2 = S2;
        #pragma unroll 8
        for (int t = 0; t < LCHUNK; ++t) {
            float v = (float)bu[t][n];
            float ns1 = fmaf(m11, s1, fmaf(m12, s2, c1 * v));
            float ns2 = fmaf(m21, s1, fmaf(m22, s2, c2 * v));
            s1 = ns1; s2 = ns2;
            bu[t][n] = (bf16)s2;                  // y in LDS
        }
    }
    __syncthreads();

    f32x4 acc2[4][2];
    #pragma unroll
    for (int i = 0; i < 4; ++i) {
        acc2[i][0] = f32x4{0.f, 0.f, 0.f, 0.f};
        acc2[i][1] = f32x4{0.f, 0.f, 0.f, 0.f};
    }
    #pragma unroll
    for (int ks = 0; ks < 8; ++ks) {
        int k = ks * 32 + lk;
        bf16x8 a[4], cfr[2];
        #pragma unroll
        for (int mf = 0; mf < 4; ++mf)
            a[mf] = *reinterpret_cast<const bf16x8*>(&bu[mf * 16 + lr][k]);
        #pragma unroll
        for (int hf = 0; hf < 2; ++hf)
            cfr[hf] = load_frag_f32(&Cm[(size_t)(h0 + hf * 16 + lr) * STATE + k]);
        #pragma unroll
        for (int mf = 0; mf < 4; ++mf)
            #pragma unroll
            for (int hf = 0; hf < 2; ++hf)
                acc2[mf][hf] = __builtin_amdgcn_mfma_f32_16x16x32_bf16(a[mf], cfr[hf], acc2[mf][hf], 0, 0, 0);
    }
    __syncthreads();                              // all bu reads done before fp32 reuse
    #pragma unroll
    for (int mf = 0; mf < 4; ++mf)
        #pragma unroll
        for (int hf = 0; hf < 2; ++hf)
            #pragma unroll
            for (int r = 0; r < 4; ++r)
                ldsF[mf * 16 + mrow + r][h0 + hf * 16 + lr] = acc2[mf][hf][r];
    __syncthreads();
    #pragma unroll
    for (int p = 0; p < 8; ++p) {
        int flat = p * 256 + tid;
        int row = flat >> 5, c4 = flat & 31;
        float4 f = *reinterpret_cast<const float4*>(&ldsF[row][c4 * 4]);
        float4 d = *reinterpret_cast<const float4*>(&Dv[c4 * 4]);
        float4 o;
        o.x = f.x + d.x * xep[p].x;
        o.y = f.y + d.y * xep[p].y;
        o.z = f.z + d.z * xep[p].z;
        o.w = f.w + d.w * xep[p].w;
        *reinterpret_cast<float4*>(&out[(size_t)(m0 + row) * HIDDEN + c4 * 4]) = o;
    }
}

extern "C" void kernel_launch(void* const* d_in, const int* in_sizes, int n_in,
                              void* d_out, int out_size, void* d_ws, size_t ws_size,
                              hipStream_t stream) {
    const float* x      = (const float*)d_in[0];
    const float* A_diag = (const float*)d_in[1];
    const float* steps  = (const float*)d_in[2];
    const float* Bm     = (const float*)d_in[3];
    const float* Cm     = (const float*)d_in[4];
    const float* Dv     = (const float*)d_in[5];
    float* out = (float*)d_out;

    char* ws = (char*)d_ws;
    const size_t CS_BYTES = (size_t)NTILE * 2 * STATE * 4;   // 2 MB
    float* cs       = (float*)ws;
    int*   sync_buf = (int*)(ws + CS_BYTES);                 // ticket + 1024 flags

    // zero ticket+flags every call (harness does not re-poison between replays)
    hipMemsetAsync(sync_buf, 0, (16 + NTILE) * sizeof(int), stream);
    hipLaunchKernelGGL(fused_k, dim3(NTILE), dim3(256), 0, stream,
                       x, A_diag, steps, Bm, Cm, Dv, cs, sync_buf, out);
}

// Round 7
// 63.400 us; speedup vs baseline: 4.3678x; 4.3678x over previous
//
#include <hip/hip_runtime.h>
#include <hip/hip_bf16.h>

#define BATCHN 16
#define SEQ 4096
#define HIDDEN 128
#define STATE 256
#define MTOT (BATCHN*SEQ)    // 65536
#define NCHUNK 64
#define LCHUNK 64            // SEQ / NCHUNK
#define NTILE (MTOT/64)      // 1024 tiles

typedef __bf16 bf16;
typedef __bf16 bf16x4 __attribute__((ext_vector_type(4)));
typedef __bf16 bf16x8 __attribute__((ext_vector_type(8)));
typedef float f32x4 __attribute__((ext_vector_type(4)));

__device__ __forceinline__ void scan_params(const float* __restrict__ A_diag,
        const float* __restrict__ steps, int n,
        float& m11, float& m12, float& m21, float& m22, float& c1, float& c2) {
    float st = 1.0f / (1.0f + expf(-steps[n]));
    float A  = fmaxf(A_diag[n], 0.0f);
    float s2A = st * st * A;
    float schur = 1.0f / (1.0f + s2A);
    m11 = 1.0f - s2A * schur;
    m12 = -st * A * schur;
    m21 = st * schur;
    m22 = schur;
    c1 = m11 * st;
    c2 = m21 * st;
}

// load 8 consecutive fp32 -> bf16x8 fragment (L2/L3-hot B/C panels)
__device__ __forceinline__ bf16x8 load_frag_f32(const float* __restrict__ src) {
    float4 a = *reinterpret_cast<const float4*>(src);
    float4 b = *reinterpret_cast<const float4*>(src + 4);
    bf16x8 r = { (bf16)a.x, (bf16)a.y, (bf16)a.z, (bf16)a.w,
                 (bf16)b.x, (bf16)b.y, (bf16)b.z, (bf16)b.w };
    return r;
}

// ---------------- K1: stage x -> GEMM1 -> Bu store -> scanA -> cs ----------------
// LDS 51 KB -> 3 blocks/CU.
__global__ __launch_bounds__(256, 3) void k1_gemm_scanA(const float* __restrict__ x,
        const float* __restrict__ A_diag, const float* __restrict__ steps,
        const float* __restrict__ Bm, float* __restrict__ cs,
        bf16* __restrict__ Bu_g) {
    __shared__ bf16 xl[64][136];
    __shared__ bf16 bu[64][264];
    const int tid = threadIdx.x;
    const int bid = blockIdx.x;
    const int m0 = bid * 64;
    const int wid = tid >> 6, lane = tid & 63;
    const int lr = lane & 15, lk = (lane >> 4) * 8;
    const int n0 = wid * 64;
    const int mrow = (lane >> 4) * 4;

    // stage x (fp32 -> bf16)
    #pragma unroll
    for (int p = 0; p < 8; ++p) {
        int flat = p * 256 + tid;                // 64 rows x 32 float4
        int row = flat >> 5, c4 = flat & 31;
        float4 v = *reinterpret_cast<const float4*>(&x[(size_t)(m0 + row) * HIDDEN + c4 * 4]);
        bf16x4 w = { (bf16)v.x, (bf16)v.y, (bf16)v.z, (bf16)v.w };
        *reinterpret_cast<bf16x4*>(&xl[row][c4 * 4]) = w;
    }
    __syncthreads();

    // GEMM1: Bu = x @ B^T (inline fp32->bf16 B frags)
    f32x4 acc[4][4];
    #pragma unroll
    for (int i = 0; i < 4; ++i)
        #pragma unroll
        for (int j = 0; j < 4; ++j) acc[i][j] = f32x4{0.f, 0.f, 0.f, 0.f};
    #pragma unroll
    for (int ks = 0; ks < 4; ++ks) {
        int k = ks * 32 + lk;
        bf16x8 a[4], bfr[4];
        #pragma unroll
        for (int mf = 0; mf < 4; ++mf)
            a[mf] = *reinterpret_cast<const bf16x8*>(&xl[mf * 16 + lr][k]);
        #pragma unroll
        for (int nf = 0; nf < 4; ++nf)
            bfr[nf] = load_frag_f32(&Bm[(size_t)(n0 + nf * 16 + lr) * HIDDEN + k]);
        #pragma unroll
        for (int mf = 0; mf < 4; ++mf)
            #pragma unroll
            for (int nf = 0; nf < 4; ++nf)
                acc[mf][nf] = __builtin_amdgcn_mfma_f32_16x16x32_bf16(a[mf], bfr[nf], acc[mf][nf], 0, 0, 0);
    }
    #pragma unroll
    for (int mf = 0; mf < 4; ++mf)
        #pragma unroll
        for (int nf = 0; nf < 4; ++nf)
            #pragma unroll
            for (int r = 0; r < 4; ++r)
                bu[mf * 16 + mrow + r][n0 + nf * 16 + lr] = (bf16)acc[mf][nf][r];

    const int n = tid;
    float m11, m12, m21, m22, c1, c2;
    scan_params(A_diag, steps, n, m11, m12, m21, m22, c1, c2);
    __syncthreads();

    // coalesced Bu store (issues first; drains under the scan)
    #pragma unroll
    for (int p = 0; p < 8; ++p) {
        int flat = p * 256 + tid;                // 64 rows x 32 chunks of 8 bf16
        int row = flat >> 5, c8 = flat & 31;
        bf16x8 v = *reinterpret_cast<const bf16x8*>(&bu[row][c8 * 8]);
        *reinterpret_cast<bf16x8*>(&Bu_g[((size_t)(m0 + row)) * STATE + c8 * 8]) = v;
    }

    // local scan (phase A), thread = state n
    float s1 = 0.f, s2 = 0.f;
    #pragma unroll 8
    for (int t = 0; t < LCHUNK; ++t) {
        float v = (float)bu[t][n];
        float ns1 = fmaf(m11, s1, fmaf(m12, s2, c1 * v));
        float ns2 = fmaf(m21, s1, fmaf(m22, s2, c2 * v));
        s1 = ns1; s2 = ns2;
    }
    size_t base = ((size_t)bid * 2) * STATE + n;  // bid == batch*NCHUNK+chunk
    cs[base] = s1;                                 // inclusive local chunk state
    cs[base + STATE] = s2;
}

// ---------------- K2: stage Bu + prefix fold + scanC + GEMM2 + D*x ----------------
// LDS 34 KB -> 4 blocks/CU. Kernel boundary guarantees cs complete & visible.
__global__ __launch_bounds__(256, 4) void k2_scan_gemm(const bf16* __restrict__ Bu_g,
        const float* __restrict__ x, const float* __restrict__ A_diag,
        const float* __restrict__ steps, const float* __restrict__ Cm,
        const float* __restrict__ cs, const float* __restrict__ Dv,
        float* __restrict__ out) {
    __shared__ bf16 bu[64][264];                  // aliased as fp32 [64][132] for epilogue
    float (*ldsF)[132] = reinterpret_cast<float(*)[132]>(&bu[0][0]);
    const int tid = threadIdx.x;
    const int bid = blockIdx.x;
    const int m0 = bid * 64;
    const int wid = tid >> 6, lane = tid & 63;
    const int lr = lane & 15, lk = (lane >> 4) * 8;
    const int h0 = wid * 32;
    const int batch = bid >> 6;
    const int chunk = bid & (NCHUNK - 1);
    const int n = tid;
    const int mrow = (lane >> 4) * 4;

    // stage Bu tile (coalesced 16B loads)
    #pragma unroll
    for (int p = 0; p < 8; ++p) {
        int flat = p * 256 + tid;
        int row = flat >> 5, c8 = flat & 31;
        bf16x8 v = *reinterpret_cast<const bf16x8*>(&Bu_g[((size_t)(m0 + row)) * STATE + c8 * 8]);
        *reinterpret_cast<bf16x8*>(&bu[row][c8 * 8]) = v;
    }

    // scan params + in-block exclusive-prefix fold (replaces the comb kernel;
    // latency hides under the Bu staging vmcnt)
    float m11, m12, m21, m22, c1, c2;
    scan_params(A_diag, steps, n, m11, m12, m21, m22, c1, c2);
    float S1 = 0.f, S2 = 0.f;
    if (chunk > 0) {
        float p11 = m11, p12 = m12, p21 = m21, p22 = m22;
        #pragma unroll
        for (int i = 0; i < 6; ++i) {             // M^64 via squaring
            float q11 = p11 * p11 + p12 * p21;
            float q12 = p11 * p12 + p12 * p22;
            float q21 = p21 * p11 + p22 * p21;
            float q22 = p21 * p12 + p22 * p22;
            p11 = q11; p12 = q12; p21 = q21; p22 = q22;
        }
        #pragma unroll 4
        for (int j = 0; j < chunk; ++j) {         // ascending j: S = M64*S + v_j
            size_t base = ((size_t)(batch * NCHUNK + j) * 2) * STATE + n;
            float q1 = cs[base], q2 = cs[base + STATE];
            float n1 = fmaf(p11, S1, fmaf(p12, S2, q1));
            float n2 = fmaf(p21, S1, fmaf(p22, S2, q2));
            S1 = n1; S2 = n2;
        }
    }
    __syncthreads();

    // scanC with true init state; overwrite bu with y (bf16)
    {
        float s1 = S1, s2 = S2;
        #pragma unroll 8
        for (int t = 0; t < LCHUNK; ++t) {
            float v = (float)bu[t][n];
            float ns1 = fmaf(m11, s1, fmaf(m12, s2, c1 * v));
            float ns2 = fmaf(m21, s1, fmaf(m22, s2, c2 * v));
            s1 = ns1; s2 = ns2;
            bu[t][n] = (bf16)s2;
        }
    }
    __syncthreads();

    // GEMM2: y @ C^T (inline fp32->bf16 C frags)
    f32x4 acc2[4][2];
    #pragma unroll
    for (int i = 0; i < 4; ++i) {
        acc2[i][0] = f32x4{0.f, 0.f, 0.f, 0.f};
        acc2[i][1] = f32x4{0.f, 0.f, 0.f, 0.f};
    }
    #pragma unroll
    for (int ks = 0; ks < 8; ++ks) {
        int k = ks * 32 + lk;
        bf16x8 a[4], cfr[2];
        #pragma unroll
        for (int mf = 0; mf < 4; ++mf)
            a[mf] = *reinterpret_cast<const bf16x8*>(&bu[mf * 16 + lr][k]);
        #pragma unroll
        for (int hf = 0; hf < 2; ++hf)
            cfr[hf] = load_frag_f32(&Cm[(size_t)(h0 + hf * 16 + lr) * STATE + k]);
        #pragma unroll
        for (int mf = 0; mf < 4; ++mf)
            #pragma unroll
            for (int hf = 0; hf < 2; ++hf)
                acc2[mf][hf] = __builtin_amdgcn_mfma_f32_16x16x32_bf16(a[mf], cfr[hf], acc2[mf][hf], 0, 0, 0);
    }
    __syncthreads();                              // all bu reads done before fp32 reuse
    #pragma unroll
    for (int mf = 0; mf < 4; ++mf)
        #pragma unroll
        for (int hf = 0; hf < 2; ++hf)
            #pragma unroll
            for (int r = 0; r < 4; ++r)
                ldsF[mf * 16 + mrow + r][h0 + hf * 16 + lr] = acc2[mf][hf][r];
    __syncthreads();

    // coalesced epilogue: out = ldsF + D*x (x re-read directly, L3-hot; no reg hoard)
    #pragma unroll
    for (int p = 0; p < 8; ++p) {
        int flat = p * 256 + tid;
        int row = flat >> 5, c4 = flat & 31;
        float4 xv = *reinterpret_cast<const float4*>(&x[(size_t)(m0 + row) * HIDDEN + c4 * 4]);
        float4 f = *reinterpret_cast<const float4*>(&ldsF[row][c4 * 4]);
        float4 d = *reinterpret_cast<const float4*>(&Dv[c4 * 4]);
        float4 o;
        o.x = f.x + d.x * xv.x;
        o.y = f.y + d.y * xv.y;
        o.z = f.z + d.z * xv.z;
        o.w = f.w + d.w * xv.w;
        *reinterpret_cast<float4*>(&out[(size_t)(m0 + row) * HIDDEN + c4 * 4]) = o;
    }
}

extern "C" void kernel_launch(void* const* d_in, const int* in_sizes, int n_in,
                              void* d_out, int out_size, void* d_ws, size_t ws_size,
                              hipStream_t stream) {
    const float* x      = (const float*)d_in[0];
    const float* A_diag = (const float*)d_in[1];
    const float* steps  = (const float*)d_in[2];
    const float* Bm     = (const float*)d_in[3];
    const float* Cm     = (const float*)d_in[4];
    const float* Dv     = (const float*)d_in[5];
    float* out = (float*)d_out;

    char* ws = (char*)d_ws;
    const size_t CS_BYTES = (size_t)NTILE * 2 * STATE * 4;   // 2 MB
    float* cs   = (float*)ws;
    bf16*  Bu_g = (bf16*)(ws + CS_BYTES);                    // 32 MB

    hipLaunchKernelGGL(k1_gemm_scanA, dim3(NTILE), dim3(256), 0, stream,
                       x, A_diag, steps, Bm, cs, Bu_g);
    hipLaunchKernelGGL(k2_scan_gemm, dim3(NTILE), dim3(256), 0, stream,
                       Bu_g, x, A_diag, steps, Cm, cs, Dv, out);
}